// Round 9
// baseline (601.063 us; speedup 1.0000x reference)
//
#include <hip/hip_runtime.h>
#include <hip/hip_bf16.h>
#include <hip/hip_cooperative_groups.h>
#include <stdint.h>

namespace cg = cooperative_groups;

#define NUM_USERS 100000
#define NUM_ITEMS 50000
#define N_NODES   150000
#define LATENT    64
#define SBERT     384
#define N_EDGES   2000000
#define OUT_OFF   (N_NODES * LATENT)   // out = d_out + OUT_OFF
#define CEB       4096                 // edges per block in count/scatter (489 blocks, 16/thread)
#define SC1B      147                  // scan blocks: 147 * 1024 = 150528 >= N_NODES
#define PBLK      2048                 // persistent spmm grid: 8 blocks/CU * 256 CU
#define PWAVES    8192
#define NPW       19                   // ceil(150000 / 8192) nodes per wave

typedef __hip_bfloat16 bf16;

__device__ __forceinline__ int ufl(int v) { return __builtin_amdgcn_readfirstlane(v); }

__device__ __forceinline__ unsigned short b16u(float f) {
    bf16 h = __float2bfloat16(f);
    return *reinterpret_cast<unsigned short*>(&h);
}

// ---------- zero degree counters ----------
__global__ void k_zero_deg(int* __restrict__ deg) {
    int i = blockIdx.x * 256 + threadIdx.x;
    if (i < N_NODES) deg[i] = 0;
}

// ---------- degree count: 2M independent global atomics (deg is 600KB, L2-resident) ----------
__global__ __launch_bounds__(256) void k_count(const int* __restrict__ dst,
                                               int* __restrict__ deg) {
    int e0 = blockIdx.x * CEB + threadIdx.x;
    int d[16];
#pragma unroll
    for (int j = 0; j < 16; ++j) {
        int e = e0 + j * 256;
        d[j] = (e < N_EDGES) ? __builtin_nontemporal_load(dst + e) : -1;
    }
#pragma unroll
    for (int j = 0; j < 16; ++j)
        if (d[j] >= 0) atomicAdd(&deg[d[j]], 1);   // fire-and-forget, pipelined
}

// ---------- 3-pass exclusive scan of deg[150000] -> rp ----------
__global__ __launch_bounds__(1024) void k_scan1(const int* __restrict__ deg,
                                                int* __restrict__ rp,
                                                int* __restrict__ bsum) {
    __shared__ int sm[1024];
    int t = threadIdx.x, b = blockIdx.x;
    int i = b * 1024 + t;
    int v = (i < N_NODES) ? deg[i] : 0;
    sm[t] = v;
    __syncthreads();
    for (int off = 1; off < 1024; off <<= 1) {
        int x = (t >= off) ? sm[t - off] : 0;
        __syncthreads();
        sm[t] += x;
        __syncthreads();
    }
    if (i < N_NODES) rp[i] = sm[t] - v;     // exclusive within block
    if (t == 1023) bsum[b] = sm[1023];      // block total
}

__global__ __launch_bounds__(256) void k_scan2(const int* __restrict__ bsum,
                                               int* __restrict__ bpre) {
    __shared__ int sm[256];
    int t = threadIdx.x;
    int v = (t < SC1B) ? bsum[t] : 0;
    sm[t] = v;
    __syncthreads();
    for (int off = 1; off < 256; off <<= 1) {
        int x = (t >= off) ? sm[t - off] : 0;
        __syncthreads();
        sm[t] += x;
        __syncthreads();
    }
    if (t < SC1B) bpre[t] = sm[t] - v;      // exclusive block prefix
}

__global__ __launch_bounds__(1024) void k_scan3(const int* __restrict__ deg,
                                                int* __restrict__ rp,
                                                int* __restrict__ cur,
                                                float* __restrict__ dis,
                                                const int* __restrict__ bpre) {
    int t = threadIdx.x, b = blockIdx.x;
    int i = b * 1024 + t;
    if (i < N_NODES) {
        int r = rp[i] + bpre[b];
        rp[i]  = r;
        cur[i] = r;
        int dg = deg[i];
        dis[i] = (dg > 0) ? rsqrtf((float)dg) : 0.0f;
    }
    if (i == 0) rp[N_NODES] = N_EDGES;
}

// ---------- scatter: cws[atomicAdd(cur[dst])] = src ----------
__global__ __launch_bounds__(256) void k_scatter(const int* __restrict__ src,
                                                 const int* __restrict__ dst,
                                                 int* __restrict__ cur,
                                                 int* __restrict__ cws) {
    int e0 = blockIdx.x * CEB + threadIdx.x;
    int s[16], d[16];
#pragma unroll
    for (int j = 0; j < 16; ++j) {
        int e = e0 + j * 256;
        if (e < N_EDGES) {
            d[j] = __builtin_nontemporal_load(dst + e);
            s[j] = __builtin_nontemporal_load(src + e);
        } else d[j] = -1;
    }
    int p[16];
#pragma unroll
    for (int j = 0; j < 16; ++j)
        if (d[j] >= 0) p[j] = atomicAdd(&cur[d[j]], 1);   // 16 independent rtn-atomics
#pragma unroll
    for (int j = 0; j < 16; ++j)
        if (d[j] >= 0) cws[p[j]] = s[j];                  // L2 absorbs 4B scatter (8MB region)
}

// ---------- copy user_emb into emb0 (float4) and y0 = bf16(dis*u) packed ----------
__global__ void k_copy_user(const float4* __restrict__ u4, const float* __restrict__ dis,
                            float4* __restrict__ out4, uint2* __restrict__ y2) {
    int i = blockIdx.x * 256 + threadIdx.x;          // float4 index; 100000*16 total
    if (i < NUM_USERS * 16) {
        float4 v = u4[i];
        out4[i] = v;                                 // emb0
        float d = dis[i >> 4];                       // 16 float4 per node
        uint2 p;
        p.x = (unsigned)b16u(d * v.x) | ((unsigned)b16u(d * v.y) << 16);
        p.y = (unsigned)b16u(d * v.z) | ((unsigned)b16u(d * v.w) << 16);
        y2[i] = p;                                   // 4 bf16 in 8 B
    }
}

// ---------- projection GEMM: 128x64 tile per block, K-tile 32; w transposed in LDS ----------
__global__ __launch_bounds__(256) void k_proj(const float* __restrict__ bert,
                                              const float* __restrict__ w,
                                              const float* __restrict__ dis,
                                              float* __restrict__ out,
                                              bf16* __restrict__ y) {
    __shared__ float sB[128][33];
    __shared__ float sW[32][64];
    const int tid  = threadIdx.x;
    const int rb   = blockIdx.x * 128;
    const int col8 = (tid & 7) * 8;
    const int rowg = (tid >> 3) * 4;

    float acc[4][8];
#pragma unroll
    for (int i = 0; i < 4; ++i)
#pragma unroll
        for (int j = 0; j < 8; ++j) acc[i][j] = 0.0f;

    for (int kb = 0; kb < SBERT; kb += 32) {
        __syncthreads();
#pragma unroll
        for (int j = 0; j < 4; ++j) {
            int idx = tid + j * 256;
            int r  = idx >> 3;
            int k4 = (idx & 7) * 4;
            int rr = min(rb + r, NUM_ITEMS - 1);
            float4 v = *(const float4*)(bert + (size_t)rr * SBERT + kb + k4);
            sB[r][k4 + 0] = v.x; sB[r][k4 + 1] = v.y;
            sB[r][k4 + 2] = v.z; sB[r][k4 + 3] = v.w;
        }
#pragma unroll
        for (int j = 0; j < 2; ++j) {
            int idx = tid + j * 256;
            int c  = idx >> 3;
            int k4 = (idx & 7) * 4;
            float4 v = *(const float4*)(w + (size_t)c * SBERT + kb + k4);
            sW[k4 + 0][c] = v.x; sW[k4 + 1][c] = v.y;
            sW[k4 + 2][c] = v.z; sW[k4 + 3][c] = v.w;
        }
        __syncthreads();
#pragma unroll
        for (int kk = 0; kk < 32; ++kk) {
            float4 w0 = *(const float4*)&sW[kk][col8];
            float4 w1 = *(const float4*)&sW[kk][col8 + 4];
#pragma unroll
            for (int i = 0; i < 4; ++i) {
                float a = sB[rowg + i][kk];
                acc[i][0] = fmaf(a, w0.x, acc[i][0]);
                acc[i][1] = fmaf(a, w0.y, acc[i][1]);
                acc[i][2] = fmaf(a, w0.z, acc[i][2]);
                acc[i][3] = fmaf(a, w0.w, acc[i][3]);
                acc[i][4] = fmaf(a, w1.x, acc[i][4]);
                acc[i][5] = fmaf(a, w1.y, acc[i][5]);
                acc[i][6] = fmaf(a, w1.z, acc[i][6]);
                acc[i][7] = fmaf(a, w1.w, acc[i][7]);
            }
        }
    }
#pragma unroll
    for (int i = 0; i < 4; ++i) {
        int r = rb + rowg + i;
        if (r < NUM_ITEMS) {
            int n = NUM_USERS + r;
            size_t o = (size_t)n * LATENT + col8;
            float d = dis[n];
            float4 f0 = make_float4(acc[i][0], acc[i][1], acc[i][2], acc[i][3]);
            float4 f1 = make_float4(acc[i][4], acc[i][5], acc[i][6], acc[i][7]);
            *(float4*)(out + o)     = f0;        // emb0 only (no acc init)
            *(float4*)(out + o + 4) = f1;
#pragma unroll
            for (int j = 0; j < 8; ++j) y[o + j] = __float2bfloat16(d * acc[i][j]);
        }
    }
}

// ---------- persistent 3-layer SpMM: acc lives in VGPRs across all layers ----------
__global__ __launch_bounds__(256, 8) void k_spmm3(const bf16* __restrict__ ye,
                                                  bf16* __restrict__ y0,
                                                  bf16* __restrict__ y1,
                                                  const int* __restrict__ rp,
                                                  const int* __restrict__ cws,
                                                  const float* __restrict__ dis,
                                                  float* __restrict__ out) {
    cg::grid_group grid = cg::this_grid();
    const int lane = threadIdx.x & 63;
    const int w    = ufl(blockIdx.x * 4 + (threadIdx.x >> 6));   // wave id 0..8191

    float acc[NPW];
#pragma unroll
    for (int k = 0; k < NPW; ++k) {
        int node = w + (k << 13);
        acc[k] = (node < N_NODES) ? out[(size_t)node * LATENT + lane] : 0.0f;  // emb0
    }

    auto layer = [&](const bf16* __restrict__ ycur, bf16* __restrict__ ynext,
                     bool final_) {
#pragma unroll
        for (int k = 0; k < NPW; ++k) {
            int node = w + (k << 13);
            if (node < N_NODES) {
                int beg  = rp[node];
                int end  = rp[node + 1];
                int last = end - 1;
                float d  = dis[node];
                float a  = 0.0f;
                for (int base = beg; base < end; base += 16) {
                    int idx[16];
#pragma unroll
                    for (int j = 0; j < 16; ++j)
                        idx[j] = cws[min(base + j, last)];
                    float v[16];
#pragma unroll
                    for (int j = 0; j < 16; ++j)
                        v[j] = __bfloat162float(ycur[(size_t)idx[j] * LATENT + lane]);
#pragma unroll
                    for (int j = 0; j < 16; ++j)
                        if (base + j <= last) a += v[j];   // wave-uniform predicate
                }
                acc[k] += d * a;
                if (!final_)
                    ynext[(size_t)node * LATENT + lane] = __float2bfloat16(d * d * a);
            }
        }
    };

    layer(ye, y0, false);
    grid.sync();
    layer(y0, y1, false);
    grid.sync();
    layer(y1, nullptr, true);

#pragma unroll
    for (int k = 0; k < NPW; ++k) {
        int node = w + (k << 13);
        if (node < N_NODES)
            out[OUT_OFF + (size_t)node * LATENT + lane] = acc[k] * 0.25f;
    }
}

// ---------- fallback SpMM (3-launch) ----------
template <bool FIRST, bool FINAL>
__global__ __launch_bounds__(256) void k_spmm(const bf16* __restrict__ y,
                                              const int* __restrict__ rp,
                                              const int* __restrict__ cws,
                                              const float* __restrict__ dis,
                                              bf16* __restrict__ yn,
                                              float* __restrict__ acc,
                                              const float* __restrict__ emb0) {
    int lane = threadIdx.x & 63;
    int node = ufl(blockIdx.x * 4 + (threadIdx.x >> 6));
    int beg = rp[node];
    int end = rp[node + 1];
    int last = end - 1;
    float d = dis[node];
    size_t o = (size_t)node * LATENT + lane;
    float accv = FIRST ? emb0[o] : acc[o];
    float a = 0.0f;
    for (int base = beg; base < end; base += 16) {
        int idx[16];
#pragma unroll
        for (int j = 0; j < 16; ++j)
            idx[j] = cws[min(base + j, last)];
        float v[16];
#pragma unroll
        for (int j = 0; j < 16; ++j)
            v[j] = __bfloat162float(y[(size_t)idx[j] * LATENT + lane]);
#pragma unroll
        for (int j = 0; j < 16; ++j)
            if (base + j <= last) a += v[j];
    }
    if (!FINAL) yn[o] = __float2bfloat16(d * d * a);
    float t = accv + d * a;
    acc[o] = FINAL ? t * 0.25f : t;
}

extern "C" void kernel_launch(void* const* d_in, const int* in_sizes, int n_in,
                              void* d_out, int out_size, void* d_ws, size_t ws_size,
                              hipStream_t stream) {
    const int*   ei    = (const int*)d_in[0];
    const float* uemb  = (const float*)d_in[1];
    const float* bert  = (const float*)d_in[2];
    const float* wproj = (const float*)d_in[3];
    float* out = (float*)d_out;

    char* ws = (char*)d_ws;
    size_t off = 0;
    auto carve = [&](size_t bytes) -> void* {
        void* p = ws + off;
        off += (bytes + 255) & ~(size_t)255;
        return p;
    };
    int*   deg  = (int*)carve(sizeof(int) * N_NODES);
    int*   rp   = (int*)carve(sizeof(int) * (N_NODES + 1));
    int*   cur  = (int*)carve(sizeof(int) * N_NODES);
    float* dis  = (float*)carve(sizeof(float) * N_NODES);
    int*   bsum = (int*)carve(sizeof(int) * SC1B);
    int*   bpre = (int*)carve(sizeof(int) * SC1B);
    int*   cws  = (int*)carve(sizeof(int) * N_EDGES);
    bf16*  ye   = (bf16*)carve(sizeof(bf16) * (size_t)N_NODES * LATENT);
    bf16*  y0   = (bf16*)carve(sizeof(bf16) * (size_t)N_NODES * LATENT);
    bf16*  y1   = (bf16*)carve(sizeof(bf16) * (size_t)N_NODES * LATENT);

    const int* srcI = ei;
    const int* dstI = ei + N_EDGES;

    const int EB = (N_EDGES + CEB - 1) / CEB;          // 489
    k_zero_deg<<<(N_NODES + 255) / 256, 256, 0, stream>>>(deg);
    k_count<<<EB, 256, 0, stream>>>(dstI, deg);
    k_scan1<<<SC1B, 1024, 0, stream>>>(deg, rp, bsum);
    k_scan2<<<1, 256, 0, stream>>>(bsum, bpre);
    k_scan3<<<SC1B, 1024, 0, stream>>>(deg, rp, cur, dis, bpre);
    k_scatter<<<EB, 256, 0, stream>>>(srcI, dstI, cur, cws);
    k_copy_user<<<(NUM_USERS * 16 + 255) / 256, 256, 0, stream>>>(
        (const float4*)uemb, dis, (float4*)out, (uint2*)ye);
    k_proj<<<(NUM_ITEMS + 127) / 128, 256, 0, stream>>>(bert, wproj, dis, out, ye);

    float* accp = out + OUT_OFF;

    static int coop_ok = -1;
    if (coop_ok < 0) {
        hipDeviceProp_t prop;
        int dev = 0;
        hipGetDevice(&dev);
        hipGetDeviceProperties(&prop, dev);
        int maxb = 0;
        hipError_t e = hipOccupancyMaxActiveBlocksPerMultiprocessor(
            &maxb, (const void*)k_spmm3, 256, 0);
        coop_ok = (e == hipSuccess && prop.cooperativeLaunch &&
                   maxb * prop.multiProcessorCount >= PBLK) ? 1 : 0;
    }

    if (coop_ok) {
        void* args[] = {(void*)&ye, (void*)&y0, (void*)&y1, (void*)&rp,
                        (void*)&cws, (void*)&dis, (void*)&out};
        hipLaunchCooperativeKernel((void*)k_spmm3, dim3(PBLK), dim3(256),
                                   args, 0, stream);
    } else {
        k_spmm<true,  false><<<N_NODES / 4, 256, 0, stream>>>(ye, rp, cws, dis, y0, accp, out);
        k_spmm<false, false><<<N_NODES / 4, 256, 0, stream>>>(y0, rp, cws, dis, y1, accp, out);
        k_spmm<false, true ><<<N_NODES / 4, 256, 0, stream>>>(y1, rp, cws, dis, y0, accp, out);
    }
}